// Round 1
// baseline (23.286 us; speedup 1.0000x reference)
//
#include <hip/hip_runtime.h>
#include <math.h>

#define N2V 32
#define BLOCK 256
#define TPT 8                 // l-values per thread
#define CHUNK (BLOCK * TPT)   // 2048 l per block

__global__ __launch_bounds__(BLOCK) void s4d_vand_kernel(
    const float* __restrict__ C,          // (H, N2, 2)
    const float* __restrict__ log_dt,     // (H,)
    const float* __restrict__ log_A_real, // (H, N2)
    const float* __restrict__ A_imag,     // (H, N2)
    float* __restrict__ K,                // (H, L)
    int L, int chunks_per_h)
{
    __shared__ float sX[N2V], sY[N2V], sCr[N2V], sCi[N2V], sRr[N2V], sRi[N2V];

    const int h     = blockIdx.x / chunks_per_h;
    const int chunk = (blockIdx.x % chunks_per_h) * CHUNK;
    const int t     = threadIdx.x;

    if (t < N2V) {
        const int n = t;
        const float dt = expf(log_dt[h]);
        const float ar = -expf(log_A_real[h * N2V + n]);  // Re(A)
        const float ai = A_imag[h * N2V + n];             // Im(A)
        const float x = ar * dt;                          // Re(dtA)
        const float y = ai * dt;                          // Im(dtA)
        // w = exp(dtA) - 1
        float sn, cs;
        sincosf(y, &sn, &cs);
        const float e  = expf(x);
        const float wr = e * cs - 1.0f;
        const float wi = e * sn;
        // w / A = w * conj(A) / |A|^2
        const float inv = 1.0f / (ar * ar + ai * ai);
        const float dr = (wr * ar + wi * ai) * inv;
        const float di = (wi * ar - wr * ai) * inv;
        // Ceff = Cc * (w/A), fold the final 2.0 scale in here
        const float cr = C[(h * N2V + n) * 2 + 0];
        const float ci = C[(h * N2V + n) * 2 + 1];
        sCr[n] = 2.0f * (cr * dr - ci * di);
        sCi[n] = 2.0f * (cr * di + ci * dr);
        // R = r^BLOCK = exp(dtA * BLOCK)
        float sR, cR;
        sincosf(y * (float)BLOCK, &sR, &cR);
        const float eR = expf(x * (float)BLOCK);
        sRr[n] = eR * cR;
        sRi[n] = eR * sR;
        sX[n] = x;
        sY[n] = y;
    }
    __syncthreads();

    const int l0 = chunk + t;
    if (l0 >= L) return;
    const float fl0 = (float)l0;

    float acc[TPT];
#pragma unroll
    for (int j = 0; j < TPT; ++j) acc[j] = 0.0f;

    for (int n = 0; n < N2V; ++n) {
        // s = Ceff * r^{l0}, r^{l0} = exp(x*l0) * (cos(y*l0) + i sin(y*l0))
        const float e = __expf(sX[n] * fl0);
        float sn, cs;
        __sincosf(sY[n] * fl0, &sn, &cs);
        const float br = e * cs, bi = e * sn;
        const float Cr = sCr[n], Ci = sCi[n];
        float sr = Cr * br - Ci * bi;
        float si = Cr * bi + Ci * br;
        const float Rr = sRr[n], Ri = sRi[n];
#pragma unroll
        for (int j = 0; j < TPT; ++j) {
            acc[j] += sr;
            const float nr = sr * Rr - si * Ri;
            const float ni = sr * Ri + si * Rr;
            sr = nr;
            si = ni;
        }
    }

    float* out = K + (size_t)h * L + l0;
#pragma unroll
    for (int j = 0; j < TPT; ++j) {
        const int l = l0 + j * BLOCK;
        if (l < L) out[(size_t)j * BLOCK] = acc[j];
    }
}

extern "C" void kernel_launch(void* const* d_in, const int* in_sizes, int n_in,
                              void* d_out, int out_size, void* d_ws, size_t ws_size,
                              hipStream_t stream) {
    // inputs: [0]=L (int scalar, unused on host), [1]=C (H,N2,2), [2]=log_dt (H,),
    //         [3]=log_A_real (H,N2), [4]=A_imag (H,N2)
    const float* C          = (const float*)d_in[1];
    const float* log_dt     = (const float*)d_in[2];
    const float* log_A_real = (const float*)d_in[3];
    const float* A_imag     = (const float*)d_in[4];
    float* K = (float*)d_out;

    const int H = in_sizes[2];            // log_dt has H elements
    const int L = out_size / H;           // output is (H, L)
    const int chunks_per_h = (L + CHUNK - 1) / CHUNK;

    dim3 grid(H * chunks_per_h);
    dim3 block(BLOCK);
    s4d_vand_kernel<<<grid, block, 0, stream>>>(C, log_dt, log_A_real, A_imag,
                                                K, L, chunks_per_h);
}

// Round 2
// 16.525 us; speedup vs baseline: 1.4091x; 1.4091x over previous
//
#include <hip/hip_runtime.h>
#include <math.h>

#define N2V 32
#define BLOCK 256
#define TPT 8                 // l-values per thread
#define CHUNK (BLOCK * TPT)   // 2048 l per block

__global__ __launch_bounds__(BLOCK) void s4d_vand_kernel(
    const float* __restrict__ C,          // (H, N2, 2)
    const float* __restrict__ log_dt,     // (H,)
    const float* __restrict__ log_A_real, // (H, N2)
    const float* __restrict__ A_imag,     // (H, N2)
    float* __restrict__ K,                // (H, L)
    int L, int chunks_per_h)
{
    // per-(n): init4 = (x, y, Cr, Ci); M[j] = (Re R^j, -Im R^j), R = exp(dtA*BLOCK)
    __shared__ float4 sInit[N2V];
    __shared__ float2 sM[N2V * TPT];

    const int h     = blockIdx.x / chunks_per_h;
    const int chunk = (blockIdx.x % chunks_per_h) * CHUNK;
    const int t     = threadIdx.x;

    if (t < N2V) {
        const int n = t;
        const float dt = expf(log_dt[h]);
        const float ar = -expf(log_A_real[h * N2V + n]);  // Re(A)
        const float ai = A_imag[h * N2V + n];             // Im(A)
        const float x = ar * dt;                          // Re(dtA)
        const float y = ai * dt;                          // Im(dtA)
        // w = exp(dtA) - 1
        float sn, cs;
        sincosf(y, &sn, &cs);
        const float e  = expf(x);
        const float wr = e * cs - 1.0f;
        const float wi = e * sn;
        // w / A = w * conj(A) / |A|^2
        const float inv = 1.0f / (ar * ar + ai * ai);
        const float dr = (wr * ar + wi * ai) * inv;
        const float di = (wi * ar - wr * ai) * inv;
        // Ceff = 2 * Cc * (w/A)
        const float cr = C[(h * N2V + n) * 2 + 0];
        const float ci = C[(h * N2V + n) * 2 + 1];
        const float Cr = 2.0f * (cr * dr - ci * di);
        const float Ci = 2.0f * (cr * di + ci * dr);
        sInit[n] = make_float4(x, y, Cr, Ci);
        // R = exp(dtA * BLOCK); table M[j] = R^j with -Im stored
        float sR, cR;
        sincosf(y * (float)BLOCK, &sR, &cR);
        const float eR = expf(x * (float)BLOCK);
        const float Rr = eR * cR;
        const float Ri = eR * sR;
        float mr = 1.0f, mi = 0.0f;
#pragma unroll
        for (int j = 0; j < TPT; ++j) {
            sM[n * TPT + j] = make_float2(mr, -mi);
            const float nmr = mr * Rr - mi * Ri;
            const float nmi = mr * Ri + mi * Rr;
            mr = nmr;
            mi = nmi;
        }
    }
    __syncthreads();

    const int l0 = chunk + t;
    const float fl0 = (float)l0;

    float acc[TPT];
#pragma unroll
    for (int j = 0; j < TPT; ++j) acc[j] = 0.0f;

#pragma unroll 8
    for (int n = 0; n < N2V; ++n) {
        const float4 ini = sInit[n];                // broadcast ds_read_b128
        const float e = __expf(ini.x * fl0);
        float sn, cs;
        __sincosf(ini.y * fl0, &sn, &cs);
        const float br = e * cs, bi = e * sn;
        const float sr = ini.z * br - ini.w * bi;   // s0 = Ceff * r^l0
        const float si = ini.z * bi + ini.w * br;
#pragma unroll
        for (int j = 0; j < TPT; ++j) {
            const float2 m = sM[n * TPT + j];       // broadcast ds_read_b64
            acc[j] = fmaf(sr, m.x, acc[j]);         // += sr*Mr
            acc[j] = fmaf(si, m.y, acc[j]);         // += si*(-Mi)
        }
    }

    float* out = K + (size_t)h * L + l0;
#pragma unroll
    for (int j = 0; j < TPT; ++j) {
        const int l = l0 + j * BLOCK;
        if (l < L) out[(size_t)j * BLOCK] = acc[j];
    }
}

extern "C" void kernel_launch(void* const* d_in, const int* in_sizes, int n_in,
                              void* d_out, int out_size, void* d_ws, size_t ws_size,
                              hipStream_t stream) {
    // inputs: [0]=L (scalar), [1]=C (H,N2,2), [2]=log_dt (H,),
    //         [3]=log_A_real (H,N2), [4]=A_imag (H,N2)
    const float* C          = (const float*)d_in[1];
    const float* log_dt     = (const float*)d_in[2];
    const float* log_A_real = (const float*)d_in[3];
    const float* A_imag     = (const float*)d_in[4];
    float* K = (float*)d_out;

    const int H = in_sizes[2];            // log_dt has H elements
    const int L = out_size / H;           // output is (H, L)
    const int chunks_per_h = (L + CHUNK - 1) / CHUNK;

    dim3 grid(H * chunks_per_h);
    dim3 block(BLOCK);
    s4d_vand_kernel<<<grid, block, 0, stream>>>(C, log_dt, log_A_real, A_imag,
                                                K, L, chunks_per_h);
}